// Round 15
// baseline (296.242 us; speedup 1.0000x reference)
//
#include <hip/hip_runtime.h>
#include <hip/hip_bf16.h>
#include <stdint.h>

#define B_   2
#define S_   2048
#define D_   1024
#define H_   16
#define DK_  64

typedef __attribute__((ext_vector_type(4))) float          f32x4;
typedef __attribute__((ext_vector_type(8))) __bf16         bf16x8;
typedef __attribute__((ext_vector_type(8))) short          short8;
typedef __attribute__((ext_vector_type(4))) unsigned short u16x4;

__device__ __forceinline__ unsigned short f2bf(float x) {
  union { float f; unsigned u; } un; un.f = x;
  unsigned r = un.u + 0x7fffu + ((un.u >> 16) & 1u);
  return (unsigned short)(r >> 16);
}

// 2^x in one v_exp_f32 (scores pre-scaled by 0.125*log2e so this IS exp(s/8))
__device__ __forceinline__ float fexp2(float x) {
  float r;
  asm("v_exp_f32 %0, %1" : "=v"(r) : "v"(x));
  return r;
}

#define WAIT_LGKM0() asm volatile("s_waitcnt lgkmcnt(0)" ::: "memory")
#define WAIT_VM0()   asm volatile("s_waitcnt vmcnt(0)" ::: "memory")
// counted: allow the current iteration's 4 attn float4-stores to stay in
// flight, force everything older (incl. the 4 prefetch loads) complete.
#define WAIT_VM4()   asm volatile("s_waitcnt vmcnt(4)" ::: "memory")
#define SCHED_PIN()  __builtin_amdgcn_sched_barrier(0)
#define BAR()        __builtin_amdgcn_s_barrier()

// async global->LDS, 16B per lane. LDS dest must be wave-uniform base (HW adds lane*16).
#define ASYNC16(gp, lp)                                                         \
  __builtin_amdgcn_global_load_lds(                                             \
      (const __attribute__((address_space(1))) unsigned int*)(const void*)(gp), \
      (__attribute__((address_space(3))) unsigned int*)(void*)(lp), 16, 0, 0)

// ---------------------------------------------------------------- zero-fill
// One 64-row band of the attn upper triangle: rows qb*64..+63 of head bh,
// cols (qb+1)*64..2047. 4 threads per row, f32x4 stores (R3-proven pattern).
__device__ __forceinline__ void zfill_band(float* __restrict__ attn,
                                           int bh, int qb, int tid) {
  const int zstart = (qb + 1) * 64;
  if (zstart >= S_) return;
  const f32x4 z4 = {0.f, 0.f, 0.f, 0.f};
  int r = tid >> 2;                       // 0..63
  int c0 = zstart + (tid & 3) * 4;
  float* rowp = attn + ((size_t)bh * S_ + qb * 64 + r) * (size_t)S_;
  for (int c = c0; c < S_; c += 16)
    *(f32x4*)(rowp + c) = z4;
}

// ---------------------------------------------------------------- fp32 -> bf16
struct Cvt3 { const float* in[3]; unsigned short* out[3]; };
struct Cvt4 { const float* in[4]; unsigned short* out[4]; };

__global__ __launch_bounds__(256) void cvt3_kernel(Cvt3 a, int n4) {
  int z = blockIdx.y;
  int i = blockIdx.x * 256 + threadIdx.x;
  if (i >= n4) return;
  f32x4 v = *(const f32x4*)(a.in[z] + (size_t)i * 4);
  u16x4 o;
  o.x = f2bf(v.x); o.y = f2bf(v.y); o.z = f2bf(v.z); o.w = f2bf(v.w);
  *(u16x4*)(a.out[z] + (size_t)i * 4) = o;
}

__global__ __launch_bounds__(256) void cvt4_kernel(Cvt4 a, int n4) {
  int z = blockIdx.y;
  int i = blockIdx.x * 256 + threadIdx.x;
  if (i >= n4) return;
  f32x4 v = *(const f32x4*)(a.in[z] + (size_t)i * 4);
  u16x4 o;
  o.x = f2bf(v.x); o.y = f2bf(v.y); o.z = f2bf(v.z); o.w = f2bf(v.w);
  *(u16x4*)(a.out[z] + (size_t)i * 4) = o;
}

// ---------------------------------------------------------------- GEMM core
// C[m,n] = sum_k A[m,k] * W[n,k]. BM=128, BN in {128,64}, BK=32, 4 waves (2x2).
// R3-proven 2-phase prefetch: STAGE next K-step at top, compute current,
// lgkmcnt(0)+vmcnt(0)+raw barrier at end.
template <int BN>
__device__ __forceinline__ void gemm_core(const unsigned short* __restrict__ A,
                                          const unsigned short* __restrict__ W,
                                          unsigned short* sA, unsigned short* sB,
                                          int mBase, int nBase, f32x4 acc[4][BN / 32]) {
  constexpr int NW = BN / 32;
  const int tid = threadIdx.x, wid = tid >> 6, lane = tid & 63;
  const int g16 = lane >> 4, l16 = lane & 15;
  const int wr = wid >> 1, wc = wid & 1;

  auto stage = [&](int buf, int k0) {
#pragma unroll
    for (int i = 0; i < 2; ++i) {
      int L = i * 256 + tid;
      int row = L >> 2;
      int gsw = (L & 3) ^ (row & 3);   // pre-swizzled global granule (rule #21)
      ASYNC16(A + (size_t)(mBase + row) * 1024 + k0 + gsw * 8,
              sA + buf * (128 * 32) + (size_t)(i * 256 + wid * 64) * 8);
    }
#pragma unroll
    for (int i = 0; i < BN / 64; ++i) {
      int L = i * 256 + tid;
      int row = L >> 2;
      int gsw = (L & 3) ^ (row & 3);
      ASYNC16(W + (size_t)(nBase + row) * 1024 + k0 + gsw * 8,
              sB + buf * (BN * 32) + (size_t)(i * 256 + wid * 64) * 8);
    }
  };

  stage(0, 0);
  WAIT_VM0();
  BAR();
  for (int t = 0; t < 32; ++t) {
    const int cur = t & 1;
    if (t < 31) stage(cur ^ 1, (t + 1) * 32);
    const unsigned short* pA = sA + cur * (128 * 32);
    const unsigned short* pB = sB + cur * (BN * 32);
    bf16x8 a[4], b[NW];
#pragma unroll
    for (int mi = 0; mi < 4; ++mi) {
      int rr = wr * 64 + mi * 16 + l16;
      a[mi] = *(const bf16x8*)&pA[rr * 32 + ((g16 ^ (rr & 3)) * 8)];
    }
#pragma unroll
    for (int ni = 0; ni < NW; ++ni) {
      int rr = wc * (BN / 2) + ni * 16 + l16;
      b[ni] = *(const bf16x8*)&pB[rr * 32 + ((g16 ^ (rr & 3)) * 8)];
    }
#pragma unroll
    for (int mi = 0; mi < 4; ++mi)
#pragma unroll
      for (int ni = 0; ni < NW; ++ni)
        acc[mi][ni] = __builtin_amdgcn_mfma_f32_16x16x32_bf16(a[mi], b[ni],
                                                              acc[mi][ni], 0, 0, 0);
    WAIT_LGKM0();   // my reads of cur retired
    WAIT_VM0();     // next tile landed
    BAR();          // all waves agree
  }
}

struct QKVArgs {
  const unsigned short* A[3];
  const unsigned short* W[3];
  unsigned short* O[3];
  float* attn;
};

// QKV projections, 2D grid (R3-proven). z=0: Q pre-scaled by 0.125*log2e.
// z=2: V written TRANSPOSED [B,H,DK,S]. Epilogue additionally zero-fills one
// attn upper-triangle band (bh 0..19) — soaks idle write-BW under compute.
__global__ __launch_bounds__(256) void gemm_qkv(QKVArgs args) {
  __shared__ unsigned short sA[2 * 128 * 32];
  __shared__ unsigned short sB[2 * 128 * 32];
  const int z = blockIdx.z;
  const int mBase = blockIdx.x * 128, nBase = blockIdx.y * 128;
  f32x4 acc[4][4];
  const f32x4 zz = {0.f, 0.f, 0.f, 0.f};
#pragma unroll
  for (int mi = 0; mi < 4; ++mi)
#pragma unroll
    for (int ni = 0; ni < 4; ++ni) acc[mi][ni] = zz;
  gemm_core<128>(args.A[z], args.W[z], sA, sB, mBase, nBase, acc);

  unsigned short* __restrict__ O = args.O[z];
  const int tid = threadIdx.x, wid = tid >> 6, lane = tid & 63;
  const int g16 = lane >> 4, l16 = lane & 15;
  const int wr = wid >> 1, wc = wid & 1;
  const float qscale = 0.125f * 1.44269504088896f;   // fold 1/sqrt(DK) and log2e
  const float sc = (z == 0) ? qscale : 1.f;
#pragma unroll
  for (int mi = 0; mi < 4; ++mi)
#pragma unroll
    for (int ni = 0; ni < 4; ++ni)
#pragma unroll
      for (int r = 0; r < 4; ++r) {
        int row = mBase + wr * 64 + mi * 16 + g16 * 4 + r;   // C row = (lane>>4)*4+reg
        int col = nBase + wc * 64 + ni * 16 + l16;           // C col = lane&15
        int bb = row >> 11, ss = row & 2047;
        int hh = col >> 6,  dd = col & 63;
        unsigned short val = f2bf(acc[mi][ni][r] * sc);
        if (z == 2)
          O[((size_t)(bb * H_ + hh) * DK_ + dd) * S_ + ss] = val;   // V^T
        else
          O[(((size_t)(bb * H_ + hh)) * S_ + ss) * DK_ + dd] = val;
      }

  // zero-fill band: flat block id over (32,8,3) grid, 640 bands = bh 0..19
  const int flat = blockIdx.x + 32 * blockIdx.y + 256 * blockIdx.z;
  if (flat < 640)
    zfill_band(args.attn, flat >> 5, flat & 31, tid);
}

// Output projection: 128x64 tile, 2D grid (32x16), f32 row-major epilogue.
// Also zero-fills attn bands for bh 20..31 (384 bands over 512 blocks).
__global__ __launch_bounds__(256) void gemm_out(const unsigned short* __restrict__ A,
                                                const unsigned short* __restrict__ W,
                                                float* __restrict__ Cout,
                                                float* __restrict__ attn) {
  __shared__ unsigned short sA[2 * 128 * 32];
  __shared__ unsigned short sB[2 * 64 * 32];
  const int mBase = blockIdx.x * 128, nBase = blockIdx.y * 64;
  f32x4 acc[4][2];
  const f32x4 zz = {0.f, 0.f, 0.f, 0.f};
#pragma unroll
  for (int mi = 0; mi < 4; ++mi)
#pragma unroll
    for (int ni = 0; ni < 2; ++ni) acc[mi][ni] = zz;
  gemm_core<64>(A, W, sA, sB, mBase, nBase, acc);

  const int tid = threadIdx.x, wid = tid >> 6, lane = tid & 63;
  const int g16 = lane >> 4, l16 = lane & 15;
  const int wr = wid >> 1, wc = wid & 1;
#pragma unroll
  for (int mi = 0; mi < 4; ++mi)
#pragma unroll
    for (int ni = 0; ni < 2; ++ni)
#pragma unroll
      for (int r = 0; r < 4; ++r) {
        int row = mBase + wr * 64 + mi * 16 + g16 * 4 + r;
        int col = nBase + wc * 32 + ni * 16 + l16;
        Cout[(size_t)row * 1024 + col] = acc[mi][ni][r];
      }

  const int flat = blockIdx.x + 32 * blockIdx.y;   // grid (32,16) -> 0..511
  if (flat < 384)
    zfill_band(attn, 20 + (flat >> 5), flat & 31, tid);
}

// ---------------------------------------------------------------- attention
// R14 structure (270.7 us): swapped QK^T (lane holds 4 consecutive attn cols
// of one q-row), float4 attn stores, packed ds_write_b64 P staging, 2-shfl
// row reduce, counted vmcnt(4) store overlap. CHANGE vs R14: zero-fill block
// REMOVED (relocated to the gemm epilogues).
__global__ __launch_bounds__(256) void attn_kernel(
    const unsigned short* __restrict__ Qh, const unsigned short* __restrict__ Kh,
    const unsigned short* __restrict__ VhT, float* __restrict__ attn,
    unsigned short* __restrict__ Oc) {
  __shared__ unsigned short sK[2 * 64 * 64];
  __shared__ unsigned short sV[2 * 64 * 64];
  __shared__ unsigned short sP[64 * 64];
  const int tid = threadIdx.x, wid = tid >> 6, lane = tid & 63;
  const int g16 = lane >> 4, l16 = lane & 15;
  const int qb = (int)gridDim.x - 1 - (int)blockIdx.x;   // heavy blocks first
  const int bh = blockIdx.y;
  const int qBase = qb * 64;
  const size_t headOff = (size_t)bh * S_ * DK_;
  const int jmax = qb;

  // Q fragments. B-operand lane mapping == A-operand mapping for 16x16x32,
  // so the load is identical to before (lane reads q-row wid*16+l16).
  bf16x8 qf[2];
  {
    const unsigned short* qp = Qh + headOff + (size_t)(qBase + wid * 16 + l16) * DK_;
    qf[0] = *(const bf16x8*)(qp + g16 * 8);
    qf[1] = *(const bf16x8*)(qp + 32 + g16 * 8);
  }
  const int scoreRow = qBase + wid * 16 + l16;      // lane's q-row (scores)
  const int rowbase  = qBase + wid * 16 + g16 * 4;  // lane's first O row (PV C)

  auto stageK = [&](int buf, int j) {
#pragma unroll
    for (int i = 0; i < 2; ++i) {
      int L = i * 256 + tid;
      int krow = L >> 3;
      int gsw = (L & 7) ^ (krow & 7);
      ASYNC16(Kh + headOff + (size_t)(j * 64 + krow) * DK_ + gsw * 8,
              sK + buf * 4096 + (size_t)(i * 256 + wid * 64) * 8);
    }
  };
  auto stageV = [&](int buf, int j) {
#pragma unroll
    for (int i = 0; i < 2; ++i) {
      int L = i * 256 + tid;
      int vrow = L >> 3;                       // dk row of V^T tile
      int gsw = (L & 7) ^ (vrow & 7);
      ASYNC16(VhT + ((size_t)bh * DK_ + vrow) * S_ + j * 64 + gsw * 8,
              sV + buf * 4096 + (size_t)(i * 256 + wid * 64) * 8);
    }
  };

  float lsum = 0.f;   // per-lane partial row-sum (row = scoreRow)

  // ---------- pass 1: row sum of 2^z (no max needed) ----------
  stageK(0, 0);
  WAIT_VM0();
  BAR();
  for (int j = 0; j <= jmax; ++j) {
    const int cur = j & 1;
    if (j < jmax) stageK(cur ^ 1, j + 1);
    const unsigned short* pK = sK + cur * 4096;
    f32x4 sc[4];
    const f32x4 zz = {0.f, 0.f, 0.f, 0.f};
#pragma unroll
    for (int ni = 0; ni < 4; ++ni) sc[ni] = zz;
#pragma unroll
    for (int ks = 0; ks < 2; ++ks)
#pragma unroll
      for (int ni = 0; ni < 4; ++ni) {
        int rr = ni * 16 + l16;
        bf16x8 kb = *(const bf16x8*)&pK[rr * 64 + (((ks * 4 + g16) ^ (rr & 7)) * 8)];
        // SWAPPED: A = K rows, B = Q -> sc[k_local][q]: k = ni*16+g16*4+r, q = l16
        sc[ni] = __builtin_amdgcn_mfma_f32_16x16x32_bf16(kb, qf[ks], sc[ni], 0, 0, 0);
      }
    if (j < jmax) {      // fully unmasked tile
#pragma unroll
      for (int ni = 0; ni < 4; ++ni)
#pragma unroll
        for (int r = 0; r < 4; ++r) lsum += fexp2(sc[ni][r]);
    } else {             // diagonal tile: causal mask
#pragma unroll
      for (int ni = 0; ni < 4; ++ni) {
        int colb = j * 64 + ni * 16 + g16 * 4;
#pragma unroll
        for (int r = 0; r < 4; ++r) {
          float e = fexp2(sc[ni][r]);
          lsum += (colb + r <= scoreRow) ? e : 0.f;
        }
      }
    }
    WAIT_LGKM0();
    WAIT_VM0();
    BAR();
  }

  // row partials live in the 4 g16 lanes of each l16 -> reduce across g16
  float invl;
  {
    float s = lsum;
    s += __shfl_xor(s, 16);
    s += __shfl_xor(s, 32);
    invl = 1.f / s;
  }

  f32x4 oacc[4];
  {
    const f32x4 zz = {0.f, 0.f, 0.f, 0.f};
#pragma unroll
    for (int ni = 0; ni < 4; ++ni) oacc[ni] = zz;
  }

  // ---------- pass 2: write attn (float4) + PV (counted-vmcnt overlap) ------
  stageK(0, 0);
  stageV(0, 0);
  WAIT_VM0();
  BAR();
  // lane's attn row pointer (row = scoreRow), and sP row
  float* const arowBase = attn + ((size_t)bh * S_ + scoreRow) * (size_t)S_;
  const int prow = wid * 16 + l16;
  for (int j = 0; j <= jmax; ++j) {
    const int cur = j & 1;
    if (j < jmax) { stageK(cur ^ 1, j + 1); stageV(cur ^ 1, j + 1); }
    SCHED_PIN();   // staging issues stay ABOVE everything below (order = age)
    const unsigned short* pK = sK + cur * 4096;
    const unsigned short* pV = sV + cur * 4096;
    f32x4 sc[4];
    const f32x4 zz = {0.f, 0.f, 0.f, 0.f};
#pragma unroll
    for (int ni = 0; ni < 4; ++ni) sc[ni] = zz;
#pragma unroll
    for (int ks = 0; ks < 2; ++ks)
#pragma unroll
      for (int ni = 0; ni < 4; ++ni) {
        int rr = ni * 16 + l16;
        bf16x8 kb = *(const bf16x8*)&pK[rr * 64 + (((ks * 4 + g16) ^ (rr & 7)) * 8)];
        sc[ni] = __builtin_amdgcn_mfma_f32_16x16x32_bf16(kb, qf[ks], sc[ni], 0, 0, 0);
      }
    const bool diag = (j == jmax);
#pragma unroll
    for (int ni = 0; ni < 4; ++ni) {
      const int colb = j * 64 + ni * 16 + g16 * 4;   // 4 consecutive attn cols
      f32x4 pv4;
      u16x4 pb4;
#pragma unroll
      for (int r = 0; r < 4; ++r) {
        float e = fexp2(sc[ni][r]) * invl;
        float p = (!diag || (colb + r <= scoreRow)) ? e : 0.f;
        pv4[r] = p;
        pb4[r] = f2bf(p);
      }
      *(f32x4*)(arowBase + colb) = pv4;              // 16B store
      const int cl = ni * 16 + g16 * 4;              // k-local col base
      *(u16x4*)&sP[prow * 64 + (((cl >> 3) ^ (prow & 7)) * 8) + (cl & 7)] = pb4;  // 8B
    }
    // PV: sP band is wave-private (write->read same wave, in-order LDS)
#pragma unroll
    for (int ks = 0; ks < 2; ++ks) {
      int pr = wid * 16 + l16;
      bf16x8 pa = *(const bf16x8*)&sP[pr * 64 + (((ks * 4 + g16) ^ (pr & 7)) * 8)];
#pragma unroll
      for (int ni = 0; ni < 4; ++ni) {
        int vr = ni * 16 + l16;
        bf16x8 vb = *(const bf16x8*)&pV[vr * 64 + (((ks * 4 + g16) ^ (vr & 7)) * 8)];
        oacc[ni] = __builtin_amdgcn_mfma_f32_16x16x32_bf16(pa, vb, oacc[ni], 0, 0, 0);
      }
    }
    WAIT_LGKM0();   // LDS reads of cur retired -> buffer reusable
    WAIT_VM4();     // 4 prefetch loads done; this iter's 4 stores may linger
    SCHED_PIN();
    BAR();          // all waves agree
  }

  // write O into concat layout [B,S,D], bf16 (oacc layout unchanged)
  const int bb = bh >> 4, hh = bh & 15;
#pragma unroll
  for (int ni = 0; ni < 4; ++ni)
#pragma unroll
    for (int r = 0; r < 4; ++r) {
      int srow = rowbase + r;
      Oc[((size_t)bb * S_ + srow) * D_ + hh * 64 + ni * 16 + l16] = f2bf(oacc[ni][r]);
    }
  // (zero-fill relocated to gemm_qkv / gemm_out epilogues)
}

// ---------------------------------------------------------------- launch
extern "C" void kernel_launch(void* const* d_in, const int* in_sizes, int n_in,
                              void* d_out, int out_size, void* d_ws, size_t ws_size,
                              hipStream_t stream) {
  const float* q  = (const float*)d_in[0];
  const float* k  = (const float*)d_in[1];
  const float* v  = (const float*)d_in[2];
  // d_in[3] = causal mask (tril ones) — structure used directly
  const float* Wq = (const float*)d_in[4];
  const float* Wk = (const float*)d_in[5];
  const float* Wv = (const float*)d_in[6];
  const float* Wo = (const float*)d_in[7];

  float* out  = (float*)d_out;
  float* attn = out + (size_t)B_ * S_ * D_;

  // workspace layout (bf16 elements), total ~67 MB
  unsigned short* ws = (unsigned short*)d_ws;
  const size_t BSD = (size_t)B_ * S_ * D_;   // 4,194,304
  const size_t DD  = (size_t)D_ * D_;        // 1,048,576
  unsigned short* qb  = ws;
  unsigned short* kb  = qb + BSD;
  unsigned short* vb  = kb + BSD;
  unsigned short* wqb = vb + BSD;
  unsigned short* wkb = wqb + DD;
  unsigned short* wvb = wkb + DD;
  unsigned short* wob = wvb + DD;
  unsigned short* Qh  = wob + DD;
  unsigned short* Kh  = Qh + BSD;
  unsigned short* VhT = Kh + BSD;
  unsigned short* Oc  = VhT + BSD;

  const int n4 = (int)(BSD / 4);   // 1,048,576
  const int w4 = (int)(DD / 4);    // 262,144
  Cvt3 c3; c3.in[0] = q; c3.in[1] = k; c3.in[2] = v;
  c3.out[0] = qb; c3.out[1] = kb; c3.out[2] = vb;
  cvt3_kernel<<<dim3(n4 / 256, 3), 256, 0, stream>>>(c3, n4);
  Cvt4 c4; c4.in[0] = Wq; c4.in[1] = Wk; c4.in[2] = Wv; c4.in[3] = Wo;
  c4.out[0] = wqb; c4.out[1] = wkb; c4.out[2] = wvb; c4.out[3] = wob;
  cvt4_kernel<<<dim3(w4 / 256, 4), 256, 0, stream>>>(c4, w4);

  QKVArgs args;
  args.A[0] = qb;  args.A[1] = kb;  args.A[2] = vb;
  args.W[0] = wqb; args.W[1] = wkb; args.W[2] = wvb;
  args.O[0] = Qh;  args.O[1] = Kh;  args.O[2] = VhT;
  args.attn = attn;
  gemm_qkv<<<dim3(32, 8, 3), 256, 0, stream>>>(args);

  attn_kernel<<<dim3(32, 32), 256, 0, stream>>>(Qh, Kh, VhT, attn, Oc);

  gemm_out<<<dim3(32, 16), 256, 0, stream>>>(Oc, wob, out, attn);
}

// Round 16
// 255.069 us; speedup vs baseline: 1.1614x; 1.1614x over previous
//
#include <hip/hip_runtime.h>
#include <hip/hip_bf16.h>
#include <stdint.h>

#define B_   2
#define S_   2048
#define D_   1024
#define H_   16
#define DK_  64

typedef __attribute__((ext_vector_type(4))) float          f32x4;
typedef __attribute__((ext_vector_type(8))) __bf16         bf16x8;
typedef __attribute__((ext_vector_type(8))) short          short8;
typedef __attribute__((ext_vector_type(4))) unsigned short u16x4;

__device__ __forceinline__ unsigned short f2bf(float x) {
  union { float f; unsigned u; } un; un.f = x;
  unsigned r = un.u + 0x7fffu + ((un.u >> 16) & 1u);
  return (unsigned short)(r >> 16);
}

// 2^x in one v_exp_f32 (scores pre-scaled by 0.125*log2e so this IS exp(s/8))
__device__ __forceinline__ float fexp2(float x) {
  float r;
  asm("v_exp_f32 %0, %1" : "=v"(r) : "v"(x));
  return r;
}

#define WAIT_LGKM0() asm volatile("s_waitcnt lgkmcnt(0)" ::: "memory")
#define WAIT_VM0()   asm volatile("s_waitcnt vmcnt(0)" ::: "memory")
// counted: allow the current iteration's 4 attn float4-stores to stay in
// flight, force everything older (incl. the 4 prefetch loads) complete.
#define WAIT_VM4()   asm volatile("s_waitcnt vmcnt(4)" ::: "memory")
#define SCHED_PIN()  __builtin_amdgcn_sched_barrier(0)
#define BAR()        __builtin_amdgcn_s_barrier()

// async global->LDS, 16B per lane. LDS dest must be wave-uniform base (HW adds lane*16).
#define ASYNC16(gp, lp)                                                         \
  __builtin_amdgcn_global_load_lds(                                             \
      (const __attribute__((address_space(1))) unsigned int*)(const void*)(gp), \
      (__attribute__((address_space(3))) unsigned int*)(void*)(lp), 16, 0, 0)

// ---------------------------------------------------------------- fp32 -> bf16
struct Cvt3 { const float* in[3]; unsigned short* out[3]; };
struct Cvt4 { const float* in[4]; unsigned short* out[4]; };

__global__ __launch_bounds__(256) void cvt3_kernel(Cvt3 a, int n4) {
  int z = blockIdx.y;
  int i = blockIdx.x * 256 + threadIdx.x;
  if (i >= n4) return;
  f32x4 v = *(const f32x4*)(a.in[z] + (size_t)i * 4);
  u16x4 o;
  o.x = f2bf(v.x); o.y = f2bf(v.y); o.z = f2bf(v.z); o.w = f2bf(v.w);
  *(u16x4*)(a.out[z] + (size_t)i * 4) = o;
}

__global__ __launch_bounds__(256) void cvt4_kernel(Cvt4 a, int n4) {
  int z = blockIdx.y;
  int i = blockIdx.x * 256 + threadIdx.x;
  if (i >= n4) return;
  f32x4 v = *(const f32x4*)(a.in[z] + (size_t)i * 4);
  u16x4 o;
  o.x = f2bf(v.x); o.y = f2bf(v.y); o.z = f2bf(v.z); o.w = f2bf(v.w);
  *(u16x4*)(a.out[z] + (size_t)i * 4) = o;
}

// ---------------------------------------------------------------- GEMM core
// C[m,n] = sum_k A[m,k] * W[n,k]. BM=128, BN in {128,64}, BK=32, 4 waves (2x2).
// R3-proven 2-phase prefetch: STAGE next K-step at top, compute current,
// lgkmcnt(0)+vmcnt(0)+raw barrier at end.
template <int BN>
__device__ __forceinline__ void gemm_core(const unsigned short* __restrict__ A,
                                          const unsigned short* __restrict__ W,
                                          unsigned short* sA, unsigned short* sB,
                                          int mBase, int nBase, f32x4 acc[4][BN / 32]) {
  constexpr int NW = BN / 32;
  const int tid = threadIdx.x, wid = tid >> 6, lane = tid & 63;
  const int g16 = lane >> 4, l16 = lane & 15;
  const int wr = wid >> 1, wc = wid & 1;

  auto stage = [&](int buf, int k0) {
#pragma unroll
    for (int i = 0; i < 2; ++i) {
      int L = i * 256 + tid;
      int row = L >> 2;
      int gsw = (L & 3) ^ (row & 3);   // pre-swizzled global granule (rule #21)
      ASYNC16(A + (size_t)(mBase + row) * 1024 + k0 + gsw * 8,
              sA + buf * (128 * 32) + (size_t)(i * 256 + wid * 64) * 8);
    }
#pragma unroll
    for (int i = 0; i < BN / 64; ++i) {
      int L = i * 256 + tid;
      int row = L >> 2;
      int gsw = (L & 3) ^ (row & 3);
      ASYNC16(W + (size_t)(nBase + row) * 1024 + k0 + gsw * 8,
              sB + buf * (BN * 32) + (size_t)(i * 256 + wid * 64) * 8);
    }
  };

  stage(0, 0);
  WAIT_VM0();
  BAR();
  for (int t = 0; t < 32; ++t) {
    const int cur = t & 1;
    if (t < 31) stage(cur ^ 1, (t + 1) * 32);
    const unsigned short* pA = sA + cur * (128 * 32);
    const unsigned short* pB = sB + cur * (BN * 32);
    bf16x8 a[4], b[NW];
#pragma unroll
    for (int mi = 0; mi < 4; ++mi) {
      int rr = wr * 64 + mi * 16 + l16;
      a[mi] = *(const bf16x8*)&pA[rr * 32 + ((g16 ^ (rr & 3)) * 8)];
    }
#pragma unroll
    for (int ni = 0; ni < NW; ++ni) {
      int rr = wc * (BN / 2) + ni * 16 + l16;
      b[ni] = *(const bf16x8*)&pB[rr * 32 + ((g16 ^ (rr & 3)) * 8)];
    }
#pragma unroll
    for (int mi = 0; mi < 4; ++mi)
#pragma unroll
      for (int ni = 0; ni < NW; ++ni)
        acc[mi][ni] = __builtin_amdgcn_mfma_f32_16x16x32_bf16(a[mi], b[ni],
                                                              acc[mi][ni], 0, 0, 0);
    WAIT_LGKM0();   // my reads of cur retired
    WAIT_VM0();     // next tile landed
    BAR();          // all waves agree
  }
}

struct QKVArgs {
  const unsigned short* A[3];
  const unsigned short* W[3];
  unsigned short* O[3];
};

// QKV projections, 2D grid (R3-proven). z=0: Q pre-scaled by 0.125*log2e.
// z=2: V written TRANSPOSED [B,H,DK,S].
__global__ __launch_bounds__(256) void gemm_qkv(QKVArgs args) {
  __shared__ unsigned short sA[2 * 128 * 32];
  __shared__ unsigned short sB[2 * 128 * 32];
  const int z = blockIdx.z;
  const int mBase = blockIdx.x * 128, nBase = blockIdx.y * 128;
  f32x4 acc[4][4];
  const f32x4 zz = {0.f, 0.f, 0.f, 0.f};
#pragma unroll
  for (int mi = 0; mi < 4; ++mi)
#pragma unroll
    for (int ni = 0; ni < 4; ++ni) acc[mi][ni] = zz;
  gemm_core<128>(args.A[z], args.W[z], sA, sB, mBase, nBase, acc);

  unsigned short* __restrict__ O = args.O[z];
  const int tid = threadIdx.x, wid = tid >> 6, lane = tid & 63;
  const int g16 = lane >> 4, l16 = lane & 15;
  const int wr = wid >> 1, wc = wid & 1;
  const float qscale = 0.125f * 1.44269504088896f;   // fold 1/sqrt(DK) and log2e
  const float sc = (z == 0) ? qscale : 1.f;
#pragma unroll
  for (int mi = 0; mi < 4; ++mi)
#pragma unroll
    for (int ni = 0; ni < 4; ++ni)
#pragma unroll
      for (int r = 0; r < 4; ++r) {
        int row = mBase + wr * 64 + mi * 16 + g16 * 4 + r;   // C row = (lane>>4)*4+reg
        int col = nBase + wc * 64 + ni * 16 + l16;           // C col = lane&15
        int bb = row >> 11, ss = row & 2047;
        int hh = col >> 6,  dd = col & 63;
        unsigned short val = f2bf(acc[mi][ni][r] * sc);
        if (z == 2)
          O[((size_t)(bb * H_ + hh) * DK_ + dd) * S_ + ss] = val;   // V^T
        else
          O[(((size_t)(bb * H_ + hh)) * S_ + ss) * DK_ + dd] = val;
      }
}

// Output projection: 128x64 tile, 2D grid (32x16), f32 row-major epilogue
__global__ __launch_bounds__(256) void gemm_out(const unsigned short* __restrict__ A,
                                                const unsigned short* __restrict__ W,
                                                float* __restrict__ Cout) {
  __shared__ unsigned short sA[2 * 128 * 32];
  __shared__ unsigned short sB[2 * 64 * 32];
  const int mBase = blockIdx.x * 128, nBase = blockIdx.y * 64;
  f32x4 acc[4][2];
  const f32x4 zz = {0.f, 0.f, 0.f, 0.f};
#pragma unroll
  for (int mi = 0; mi < 4; ++mi)
#pragma unroll
    for (int ni = 0; ni < 2; ++ni) acc[mi][ni] = zz;
  gemm_core<64>(A, W, sA, sB, mBase, nBase, acc);

  const int tid = threadIdx.x, wid = tid >> 6, lane = tid & 63;
  const int g16 = lane >> 4, l16 = lane & 15;
  const int wr = wid >> 1, wc = wid & 1;
#pragma unroll
  for (int mi = 0; mi < 4; ++mi)
#pragma unroll
    for (int ni = 0; ni < 2; ++ni)
#pragma unroll
      for (int r = 0; r < 4; ++r) {
        int row = mBase + wr * 64 + mi * 16 + g16 * 4 + r;
        int col = nBase + wc * 32 + ni * 16 + l16;
        Cout[(size_t)row * 1024 + col] = acc[mi][ni][r];
      }
}

// ---------------------------------------------------------------- attention
// Exact R14 kernel (270.7 us) with ONE change: diagonal qb remap
// qb = (x + y) & 31 (bijective per bh). Per-block work is ~(qb+1) tile-iters
// + (31-qb) zfill units; the old qb = f(x) mapping made round-robin block->CU
// assignment give every CU 4 SAME-qb blocks (32x work spread). The diagonal
// remap spreads qbs {b, b+8, b+16, b+24} across each CU's blocks, and the
// zfill (anti-correlated with compute) flattens the rest.
__global__ __launch_bounds__(256) void attn_kernel(
    const unsigned short* __restrict__ Qh, const unsigned short* __restrict__ Kh,
    const unsigned short* __restrict__ VhT, float* __restrict__ attn,
    unsigned short* __restrict__ Oc) {
  __shared__ unsigned short sK[2 * 64 * 64];
  __shared__ unsigned short sV[2 * 64 * 64];
  __shared__ unsigned short sP[64 * 64];
  const int tid = threadIdx.x, wid = tid >> 6, lane = tid & 63;
  const int g16 = lane >> 4, l16 = lane & 15;
  const int qb = (int)((blockIdx.x + blockIdx.y) & 31);   // diagonal remap
  const int bh = blockIdx.y;
  const int qBase = qb * 64;
  const size_t headOff = (size_t)bh * S_ * DK_;
  const int jmax = qb;

  // Q fragments. B-operand lane mapping == A-operand mapping for 16x16x32,
  // so the load is identical to before (lane reads q-row wid*16+l16).
  bf16x8 qf[2];
  {
    const unsigned short* qp = Qh + headOff + (size_t)(qBase + wid * 16 + l16) * DK_;
    qf[0] = *(const bf16x8*)(qp + g16 * 8);
    qf[1] = *(const bf16x8*)(qp + 32 + g16 * 8);
  }
  const int scoreRow = qBase + wid * 16 + l16;      // lane's q-row (scores)
  const int rowbase  = qBase + wid * 16 + g16 * 4;  // lane's first O row (PV C)

  auto stageK = [&](int buf, int j) {
#pragma unroll
    for (int i = 0; i < 2; ++i) {
      int L = i * 256 + tid;
      int krow = L >> 3;
      int gsw = (L & 7) ^ (krow & 7);
      ASYNC16(Kh + headOff + (size_t)(j * 64 + krow) * DK_ + gsw * 8,
              sK + buf * 4096 + (size_t)(i * 256 + wid * 64) * 8);
    }
  };
  auto stageV = [&](int buf, int j) {
#pragma unroll
    for (int i = 0; i < 2; ++i) {
      int L = i * 256 + tid;
      int vrow = L >> 3;                       // dk row of V^T tile
      int gsw = (L & 7) ^ (vrow & 7);
      ASYNC16(VhT + ((size_t)bh * DK_ + vrow) * S_ + j * 64 + gsw * 8,
              sV + buf * 4096 + (size_t)(i * 256 + wid * 64) * 8);
    }
  };

  float lsum = 0.f;   // per-lane partial row-sum (row = scoreRow)

  // ---------- pass 1: row sum of 2^z (no max needed) ----------
  stageK(0, 0);
  WAIT_VM0();
  BAR();
  for (int j = 0; j <= jmax; ++j) {
    const int cur = j & 1;
    if (j < jmax) stageK(cur ^ 1, j + 1);
    const unsigned short* pK = sK + cur * 4096;
    f32x4 sc[4];
    const f32x4 zz = {0.f, 0.f, 0.f, 0.f};
#pragma unroll
    for (int ni = 0; ni < 4; ++ni) sc[ni] = zz;
#pragma unroll
    for (int ks = 0; ks < 2; ++ks)
#pragma unroll
      for (int ni = 0; ni < 4; ++ni) {
        int rr = ni * 16 + l16;
        bf16x8 kb = *(const bf16x8*)&pK[rr * 64 + (((ks * 4 + g16) ^ (rr & 7)) * 8)];
        // SWAPPED: A = K rows, B = Q -> sc[k_local][q]: k = ni*16+g16*4+r, q = l16
        sc[ni] = __builtin_amdgcn_mfma_f32_16x16x32_bf16(kb, qf[ks], sc[ni], 0, 0, 0);
      }
    if (j < jmax) {      // fully unmasked tile
#pragma unroll
      for (int ni = 0; ni < 4; ++ni)
#pragma unroll
        for (int r = 0; r < 4; ++r) lsum += fexp2(sc[ni][r]);
    } else {             // diagonal tile: causal mask
#pragma unroll
      for (int ni = 0; ni < 4; ++ni) {
        int colb = j * 64 + ni * 16 + g16 * 4;
#pragma unroll
        for (int r = 0; r < 4; ++r) {
          float e = fexp2(sc[ni][r]);
          lsum += (colb + r <= scoreRow) ? e : 0.f;
        }
      }
    }
    WAIT_LGKM0();
    WAIT_VM0();
    BAR();
  }

  // row partials live in the 4 g16 lanes of each l16 -> reduce across g16
  float invl;
  {
    float s = lsum;
    s += __shfl_xor(s, 16);
    s += __shfl_xor(s, 32);
    invl = 1.f / s;
  }

  f32x4 oacc[4];
  {
    const f32x4 zz = {0.f, 0.f, 0.f, 0.f};
#pragma unroll
    for (int ni = 0; ni < 4; ++ni) oacc[ni] = zz;
  }

  // ---------- pass 2: write attn (float4) + PV (counted-vmcnt overlap) ------
  stageK(0, 0);
  stageV(0, 0);
  WAIT_VM0();
  BAR();
  // lane's attn row pointer (row = scoreRow), and sP row
  float* const arowBase = attn + ((size_t)bh * S_ + scoreRow) * (size_t)S_;
  const int prow = wid * 16 + l16;
  for (int j = 0; j <= jmax; ++j) {
    const int cur = j & 1;
    if (j < jmax) { stageK(cur ^ 1, j + 1); stageV(cur ^ 1, j + 1); }
    SCHED_PIN();   // staging issues stay ABOVE everything below (order = age)
    const unsigned short* pK = sK + cur * 4096;
    const unsigned short* pV = sV + cur * 4096;
    f32x4 sc[4];
    const f32x4 zz = {0.f, 0.f, 0.f, 0.f};
#pragma unroll
    for (int ni = 0; ni < 4; ++ni) sc[ni] = zz;
#pragma unroll
    for (int ks = 0; ks < 2; ++ks)
#pragma unroll
      for (int ni = 0; ni < 4; ++ni) {
        int rr = ni * 16 + l16;
        bf16x8 kb = *(const bf16x8*)&pK[rr * 64 + (((ks * 4 + g16) ^ (rr & 7)) * 8)];
        sc[ni] = __builtin_amdgcn_mfma_f32_16x16x32_bf16(kb, qf[ks], sc[ni], 0, 0, 0);
      }
    const bool diag = (j == jmax);
#pragma unroll
    for (int ni = 0; ni < 4; ++ni) {
      const int colb = j * 64 + ni * 16 + g16 * 4;   // 4 consecutive attn cols
      f32x4 pv4;
      u16x4 pb4;
#pragma unroll
      for (int r = 0; r < 4; ++r) {
        float e = fexp2(sc[ni][r]) * invl;
        float p = (!diag || (colb + r <= scoreRow)) ? e : 0.f;
        pv4[r] = p;
        pb4[r] = f2bf(p);
      }
      *(f32x4*)(arowBase + colb) = pv4;              // 16B store
      const int cl = ni * 16 + g16 * 4;              // k-local col base
      *(u16x4*)&sP[prow * 64 + (((cl >> 3) ^ (prow & 7)) * 8) + (cl & 7)] = pb4;  // 8B
    }
    // PV: sP band is wave-private (write->read same wave, in-order LDS)
#pragma unroll
    for (int ks = 0; ks < 2; ++ks) {
      int pr = wid * 16 + l16;
      bf16x8 pa = *(const bf16x8*)&sP[pr * 64 + (((ks * 4 + g16) ^ (pr & 7)) * 8)];
#pragma unroll
      for (int ni = 0; ni < 4; ++ni) {
        int vr = ni * 16 + l16;
        bf16x8 vb = *(const bf16x8*)&pV[vr * 64 + (((ks * 4 + g16) ^ (vr & 7)) * 8)];
        oacc[ni] = __builtin_amdgcn_mfma_f32_16x16x32_bf16(pa, vb, oacc[ni], 0, 0, 0);
      }
    }
    WAIT_LGKM0();   // LDS reads of cur retired -> buffer reusable
    WAIT_VM4();     // 4 prefetch loads done; this iter's 4 stores may linger
    SCHED_PIN();
    BAR();          // all waves agree
  }

  // write O into concat layout [B,S,D], bf16 (oacc layout unchanged)
  const int bb = bh >> 4, hh = bh & 15;
#pragma unroll
  for (int ni = 0; ni < 4; ++ni)
#pragma unroll
    for (int r = 0; r < 4; ++r) {
      int srow = rowbase + r;
      Oc[((size_t)bb * S_ + srow) * D_ + hh * 64 + ni * 16 + l16] = f2bf(oacc[ni][r]);
    }

  // zero-fill above-diagonal attn columns (div-free: 4 threads per row)
  const int zstart = (jmax + 1) * 64;
  if (zstart < S_) {
    const f32x4 z4 = {0.f, 0.f, 0.f, 0.f};
    int r = tid >> 2;
    int c0 = zstart + (tid & 3) * 4;
    float* rowp = attn + ((size_t)bh * S_ + qBase + r) * (size_t)S_;
    for (int c = c0; c < S_; c += 16)
      *(f32x4*)(rowp + c) = z4;
  }
}

// ---------------------------------------------------------------- launch
extern "C" void kernel_launch(void* const* d_in, const int* in_sizes, int n_in,
                              void* d_out, int out_size, void* d_ws, size_t ws_size,
                              hipStream_t stream) {
  const float* q  = (const float*)d_in[0];
  const float* k  = (const float*)d_in[1];
  const float* v  = (const float*)d_in[2];
  // d_in[3] = causal mask (tril ones) — structure used directly
  const float* Wq = (const float*)d_in[4];
  const float* Wk = (const float*)d_in[5];
  const float* Wv = (const float*)d_in[6];
  const float* Wo = (const float*)d_in[7];

  float* out  = (float*)d_out;
  float* attn = out + (size_t)B_ * S_ * D_;

  // workspace layout (bf16 elements), total ~67 MB
  unsigned short* ws = (unsigned short*)d_ws;
  const size_t BSD = (size_t)B_ * S_ * D_;   // 4,194,304
  const size_t DD  = (size_t)D_ * D_;        // 1,048,576
  unsigned short* qb  = ws;
  unsigned short* kb  = qb + BSD;
  unsigned short* vb  = kb + BSD;
  unsigned short* wqb = vb + BSD;
  unsigned short* wkb = wqb + DD;
  unsigned short* wvb = wkb + DD;
  unsigned short* wob = wvb + DD;
  unsigned short* Qh  = wob + DD;
  unsigned short* Kh  = Qh + BSD;
  unsigned short* VhT = Kh + BSD;
  unsigned short* Oc  = VhT + BSD;

  const int n4 = (int)(BSD / 4);   // 1,048,576
  const int w4 = (int)(DD / 4);    // 262,144
  Cvt3 c3; c3.in[0] = q; c3.in[1] = k; c3.in[2] = v;
  c3.out[0] = qb; c3.out[1] = kb; c3.out[2] = vb;
  cvt3_kernel<<<dim3(n4 / 256, 3), 256, 0, stream>>>(c3, n4);
  Cvt4 c4; c4.in[0] = Wq; c4.in[1] = Wk; c4.in[2] = Wv; c4.in[3] = Wo;
  c4.out[0] = wqb; c4.out[1] = wkb; c4.out[2] = wvb; c4.out[3] = wob;
  cvt4_kernel<<<dim3(w4 / 256, 4), 256, 0, stream>>>(c4, w4);

  QKVArgs args;
  args.A[0] = qb;  args.A[1] = kb;  args.A[2] = vb;
  args.W[0] = wqb; args.W[1] = wkb; args.W[2] = wvb;
  args.O[0] = Qh;  args.O[1] = Kh;  args.O[2] = VhT;
  gemm_qkv<<<dim3(32, 8, 3), 256, 0, stream>>>(args);

  attn_kernel<<<dim3(32, 32), 256, 0, stream>>>(Qh, Kh, VhT, attn, Oc);

  gemm_out<<<dim3(32, 16), 256, 0, stream>>>(Oc, wob, out);
}

// Round 18
// 251.640 us; speedup vs baseline: 1.1772x; 1.0136x over previous
//
#include <hip/hip_runtime.h>
#include <hip/hip_bf16.h>
#include <stdint.h>

#define B_   2
#define S_   2048
#define D_   1024
#define H_   16
#define DK_  64

typedef __attribute__((ext_vector_type(4))) float          f32x4;
typedef __attribute__((ext_vector_type(8))) __bf16         bf16x8;
typedef __attribute__((ext_vector_type(8))) short          short8;
typedef __attribute__((ext_vector_type(4))) unsigned short u16x4;

__device__ __forceinline__ unsigned short f2bf(float x) {
  union { float f; unsigned u; } un; un.f = x;
  unsigned r = un.u + 0x7fffu + ((un.u >> 16) & 1u);
  return (unsigned short)(r >> 16);
}

// 2^x in one v_exp_f32 (scores pre-scaled by 0.125*log2e so this IS exp(s/8))
__device__ __forceinline__ float fexp2(float x) {
  float r;
  asm("v_exp_f32 %0, %1" : "=v"(r) : "v"(x));
  return r;
}

#define WAIT_LGKM0() asm volatile("s_waitcnt lgkmcnt(0)" ::: "memory")
#define WAIT_VM0()   asm volatile("s_waitcnt vmcnt(0)" ::: "memory")
// pass-1: drain to depth-1 at the barrier (allow only the newest stage's 2 ops)
#define WAIT_VM2()   asm volatile("s_waitcnt vmcnt(2)" ::: "memory")
// pass-2: allow the current iteration's 4 attn float4-stores to stay in
// flight, force everything older (incl. the 4 prefetch loads) complete.
#define WAIT_VM4()   asm volatile("s_waitcnt vmcnt(4)" ::: "memory")
#define SCHED_PIN()  __builtin_amdgcn_sched_barrier(0)
#define BAR()        __builtin_amdgcn_s_barrier()

// async global->LDS, 16B per lane. LDS dest must be wave-uniform base (HW adds lane*16).
#define ASYNC16(gp, lp)                                                         \
  __builtin_amdgcn_global_load_lds(                                             \
      (const __attribute__((address_space(1))) unsigned int*)(const void*)(gp), \
      (__attribute__((address_space(3))) unsigned int*)(void*)(lp), 16, 0, 0)

// ---------------------------------------------------------------- fp32 -> bf16
struct Cvt3 { const float* in[3]; unsigned short* out[3]; };
struct Cvt4 { const float* in[4]; unsigned short* out[4]; };

__global__ __launch_bounds__(256) void cvt3_kernel(Cvt3 a, int n4) {
  int z = blockIdx.y;
  int i = blockIdx.x * 256 + threadIdx.x;
  if (i >= n4) return;
  f32x4 v = *(const f32x4*)(a.in[z] + (size_t)i * 4);
  u16x4 o;
  o.x = f2bf(v.x); o.y = f2bf(v.y); o.z = f2bf(v.z); o.w = f2bf(v.w);
  *(u16x4*)(a.out[z] + (size_t)i * 4) = o;
}

__global__ __launch_bounds__(256) void cvt4_kernel(Cvt4 a, int n4) {
  int z = blockIdx.y;
  int i = blockIdx.x * 256 + threadIdx.x;
  if (i >= n4) return;
  f32x4 v = *(const f32x4*)(a.in[z] + (size_t)i * 4);
  u16x4 o;
  o.x = f2bf(v.x); o.y = f2bf(v.y); o.z = f2bf(v.z); o.w = f2bf(v.w);
  *(u16x4*)(a.out[z] + (size_t)i * 4) = o;
}

// ---------------------------------------------------------------- GEMM core
// C[m,n] = sum_k A[m,k] * W[n,k]. BM=128, BN in {128,64}, BK=32, 4 waves (2x2).
// R3-proven 2-phase prefetch: STAGE next K-step at top, compute current,
// lgkmcnt(0)+vmcnt(0)+raw barrier at end.
template <int BN>
__device__ __forceinline__ void gemm_core(const unsigned short* __restrict__ A,
                                          const unsigned short* __restrict__ W,
                                          unsigned short* sA, unsigned short* sB,
                                          int mBase, int nBase, f32x4 acc[4][BN / 32]) {
  constexpr int NW = BN / 32;
  const int tid = threadIdx.x, wid = tid >> 6, lane = tid & 63;
  const int g16 = lane >> 4, l16 = lane & 15;
  const int wr = wid >> 1, wc = wid & 1;

  auto stage = [&](int buf, int k0) {
#pragma unroll
    for (int i = 0; i < 2; ++i) {
      int L = i * 256 + tid;
      int row = L >> 2;
      int gsw = (L & 3) ^ (row & 3);   // pre-swizzled global granule (rule #21)
      ASYNC16(A + (size_t)(mBase + row) * 1024 + k0 + gsw * 8,
              sA + buf * (128 * 32) + (size_t)(i * 256 + wid * 64) * 8);
    }
#pragma unroll
    for (int i = 0; i < BN / 64; ++i) {
      int L = i * 256 + tid;
      int row = L >> 2;
      int gsw = (L & 3) ^ (row & 3);
      ASYNC16(W + (size_t)(nBase + row) * 1024 + k0 + gsw * 8,
              sB + buf * (BN * 32) + (size_t)(i * 256 + wid * 64) * 8);
    }
  };

  stage(0, 0);
  WAIT_VM0();
  BAR();
  for (int t = 0; t < 32; ++t) {
    const int cur = t & 1;
    if (t < 31) stage(cur ^ 1, (t + 1) * 32);
    const unsigned short* pA = sA + cur * (128 * 32);
    const unsigned short* pB = sB + cur * (BN * 32);
    bf16x8 a[4], b[NW];
#pragma unroll
    for (int mi = 0; mi < 4; ++mi) {
      int rr = wr * 64 + mi * 16 + l16;
      a[mi] = *(const bf16x8*)&pA[rr * 32 + ((g16 ^ (rr & 3)) * 8)];
    }
#pragma unroll
    for (int ni = 0; ni < NW; ++ni) {
      int rr = wc * (BN / 2) + ni * 16 + l16;
      b[ni] = *(const bf16x8*)&pB[rr * 32 + ((g16 ^ (rr & 3)) * 8)];
    }
#pragma unroll
    for (int mi = 0; mi < 4; ++mi)
#pragma unroll
      for (int ni = 0; ni < NW; ++ni)
        acc[mi][ni] = __builtin_amdgcn_mfma_f32_16x16x32_bf16(a[mi], b[ni],
                                                              acc[mi][ni], 0, 0, 0);
    WAIT_LGKM0();   // my reads of cur retired
    WAIT_VM0();     // next tile landed
    BAR();          // all waves agree
  }
}

struct QKVArgs {
  const unsigned short* A[3];
  const unsigned short* W[3];
  unsigned short* O[3];
};

// QKV projections, 2D grid (R3-proven). z=0: Q pre-scaled by 0.125*log2e.
// z=2: V written TRANSPOSED [B,H,DK,S].
__global__ __launch_bounds__(256) void gemm_qkv(QKVArgs args) {
  __shared__ unsigned short sA[2 * 128 * 32];
  __shared__ unsigned short sB[2 * 128 * 32];
  const int z = blockIdx.z;
  const int mBase = blockIdx.x * 128, nBase = blockIdx.y * 128;
  f32x4 acc[4][4];
  const f32x4 zz = {0.f, 0.f, 0.f, 0.f};
#pragma unroll
  for (int mi = 0; mi < 4; ++mi)
#pragma unroll
    for (int ni = 0; ni < 4; ++ni) acc[mi][ni] = zz;
  gemm_core<128>(args.A[z], args.W[z], sA, sB, mBase, nBase, acc);

  unsigned short* __restrict__ O = args.O[z];
  const int tid = threadIdx.x, wid = tid >> 6, lane = tid & 63;
  const int g16 = lane >> 4, l16 = lane & 15;
  const int wr = wid >> 1, wc = wid & 1;
  const float qscale = 0.125f * 1.44269504088896f;   // fold 1/sqrt(DK) and log2e
  const float sc = (z == 0) ? qscale : 1.f;
#pragma unroll
  for (int mi = 0; mi < 4; ++mi)
#pragma unroll
    for (int ni = 0; ni < 4; ++ni)
#pragma unroll
      for (int r = 0; r < 4; ++r) {
        int row = mBase + wr * 64 + mi * 16 + g16 * 4 + r;   // C row = (lane>>4)*4+reg
        int col = nBase + wc * 64 + ni * 16 + l16;           // C col = lane&15
        int bb = row >> 11, ss = row & 2047;
        int hh = col >> 6,  dd = col & 63;
        unsigned short val = f2bf(acc[mi][ni][r] * sc);
        if (z == 2)
          O[((size_t)(bb * H_ + hh) * DK_ + dd) * S_ + ss] = val;   // V^T
        else
          O[(((size_t)(bb * H_ + hh)) * S_ + ss) * DK_ + dd] = val;
      }
}

// Output projection: 128x64 tile, 2D grid (32x16), f32 row-major epilogue
__global__ __launch_bounds__(256) void gemm_out(const unsigned short* __restrict__ A,
                                                const unsigned short* __restrict__ W,
                                                float* __restrict__ Cout) {
  __shared__ unsigned short sA[2 * 128 * 32];
  __shared__ unsigned short sB[2 * 64 * 32];
  const int mBase = blockIdx.x * 128, nBase = blockIdx.y * 64;
  f32x4 acc[4][2];
  const f32x4 zz = {0.f, 0.f, 0.f, 0.f};
#pragma unroll
  for (int mi = 0; mi < 4; ++mi)
#pragma unroll
    for (int ni = 0; ni < 2; ++ni) acc[mi][ni] = zz;
  gemm_core<64>(A, W, sA, sB, mBase, nBase, acc);

  const int tid = threadIdx.x, wid = tid >> 6, lane = tid & 63;
  const int g16 = lane >> 4, l16 = lane & 15;
  const int wr = wid >> 1, wc = wid & 1;
#pragma unroll
  for (int mi = 0; mi < 4; ++mi)
#pragma unroll
    for (int ni = 0; ni < 2; ++ni)
#pragma unroll
      for (int r = 0; r < 4; ++r) {
        int row = mBase + wr * 64 + mi * 16 + g16 * 4 + r;
        int col = nBase + wc * 32 + ni * 16 + l16;
        Cout[(size_t)row * 1024 + col] = acc[mi][ni][r];
      }
}

// ---------------------------------------------------------------- attention
// R16 kernel (255 us) + pass-1 quad K-buffer with 2-deep prefetch and counted
// vmcnt(2) drain at the barrier (stage(j) must land only by end of iter j-1's
// barrier -> one full iteration of load slack). LDS pointer selection is done
// with inline offset arithmetic (sKV + off) — a const array of LDS pointers
// does not compile (addrspacecast static initializer, R17 failure).
// Buffer-reuse: buf[j&3] read at iter j (retired via lgkm(0)+barrier), re-
// written by stage issued at iter j+2, two barriers later. All waves' stage(j)
// complete by their vmcnt(2) BEFORE the barrier opening iter j.
__global__ __launch_bounds__(256) void attn_kernel(
    const unsigned short* __restrict__ Qh, const unsigned short* __restrict__ Kh,
    const unsigned short* __restrict__ VhT, float* __restrict__ attn,
    unsigned short* __restrict__ Oc) {
  __shared__ unsigned short sKV[4 * 64 * 64];   // pass1: 4 K-bufs; pass2: K dbuf + V dbuf
  __shared__ unsigned short sP[64 * 64];
  const int tid = threadIdx.x, wid = tid >> 6, lane = tid & 63;
  const int g16 = lane >> 4, l16 = lane & 15;
  const int qb = (int)((blockIdx.x + blockIdx.y) & 31);   // diagonal remap
  const int bh = blockIdx.y;
  const int qBase = qb * 64;
  const size_t headOff = (size_t)bh * S_ * DK_;
  const int jmax = qb;

  // Q fragments. B-operand lane mapping == A-operand mapping for 16x16x32,
  // so the load is identical to before (lane reads q-row wid*16+l16).
  bf16x8 qf[2];
  {
    const unsigned short* qp = Qh + headOff + (size_t)(qBase + wid * 16 + l16) * DK_;
    qf[0] = *(const bf16x8*)(qp + g16 * 8);
    qf[1] = *(const bf16x8*)(qp + 32 + g16 * 8);
  }
  const int scoreRow = qBase + wid * 16 + l16;      // lane's q-row (scores)
  const int rowbase  = qBase + wid * 16 + g16 * 4;  // lane's first O row (PV C)

  // stage one 64x64 K tile into LDS at byte-offset bufOff (elements)
  auto stageKb = [&](int bufOff, int j) {
#pragma unroll
    for (int i = 0; i < 2; ++i) {
      int L = i * 256 + tid;
      int krow = L >> 3;
      int gsw = (L & 7) ^ (krow & 7);
      ASYNC16(Kh + headOff + (size_t)(j * 64 + krow) * DK_ + gsw * 8,
              sKV + bufOff + (size_t)(i * 256 + wid * 64) * 8);
    }
  };
  auto stageVb = [&](int bufOff, int j) {
#pragma unroll
    for (int i = 0; i < 2; ++i) {
      int L = i * 256 + tid;
      int vrow = L >> 3;                       // dk row of V^T tile
      int gsw = (L & 7) ^ (vrow & 7);
      ASYNC16(VhT + ((size_t)bh * DK_ + vrow) * S_ + j * 64 + gsw * 8,
              sKV + bufOff + (size_t)(i * 256 + wid * 64) * 8);
    }
  };

  float lsum = 0.f;   // per-lane partial row-sum (row = scoreRow)

  // ---------- pass 1: row sum of 2^z — quad-buffer, 2-deep prefetch ----------
  stageKb(0, 0);
  stageKb(4096, (jmax >= 1) ? 1 : jmax);
  WAIT_VM2();   // tile 0 landed (newest stage's 2 ops may linger)
  BAR();
  for (int j = 0; j <= jmax; ++j) {
    stageKb(((j + 2) & 3) * 4096, (j + 2 <= jmax) ? (j + 2) : jmax);   // clamped tail
    SCHED_PIN();   // stage issues stay oldest among this iter's VM ops
    const unsigned short* pK = sKV + (j & 3) * 4096;
    f32x4 sc[4];
    const f32x4 zz = {0.f, 0.f, 0.f, 0.f};
#pragma unroll
    for (int ni = 0; ni < 4; ++ni) sc[ni] = zz;
#pragma unroll
    for (int ks = 0; ks < 2; ++ks)
#pragma unroll
      for (int ni = 0; ni < 4; ++ni) {
        int rr = ni * 16 + l16;
        bf16x8 kb = *(const bf16x8*)&pK[rr * 64 + (((ks * 4 + g16) ^ (rr & 7)) * 8)];
        // SWAPPED: A = K rows, B = Q -> sc[k_local][q]: k = ni*16+g16*4+r, q = l16
        sc[ni] = __builtin_amdgcn_mfma_f32_16x16x32_bf16(kb, qf[ks], sc[ni], 0, 0, 0);
      }
    if (j < jmax) {      // fully unmasked tile
#pragma unroll
      for (int ni = 0; ni < 4; ++ni)
#pragma unroll
        for (int r = 0; r < 4; ++r) lsum += fexp2(sc[ni][r]);
    } else {             // diagonal tile: causal mask
#pragma unroll
      for (int ni = 0; ni < 4; ++ni) {
        int colb = j * 64 + ni * 16 + g16 * 4;
#pragma unroll
        for (int r = 0; r < 4; ++r) {
          float e = fexp2(sc[ni][r]);
          lsum += (colb + r <= scoreRow) ? e : 0.f;
        }
      }
    }
    WAIT_LGKM0();   // my reads of buf[j&3] retired
    WAIT_VM2();     // stage(j+1) landed (stage(j+2)'s 2 ops may linger)
    SCHED_PIN();
    BAR();          // all waves agree -> buf[(j+1)&3] readable next iter
  }

  // row partials live in the 4 g16 lanes of each l16 -> reduce across g16
  float invl;
  {
    float s = lsum;
    s += __shfl_xor(s, 16);
    s += __shfl_xor(s, 32);
    invl = 1.f / s;
  }

  f32x4 oacc[4];
  {
    const f32x4 zz = {0.f, 0.f, 0.f, 0.f};
#pragma unroll
    for (int ni = 0; ni < 4; ++ni) oacc[ni] = zz;
  }

  // ---------- pass 2: write attn (float4) + PV (counted-vmcnt overlap) ------
  // K double-buffer at offsets {0, 4096}, V double-buffer at {8192, 12288}.
  stageKb(0, 0);
  stageVb(8192, 0);
  WAIT_VM0();
  BAR();
  // lane's attn row pointer (row = scoreRow), and sP row
  float* const arowBase = attn + ((size_t)bh * S_ + scoreRow) * (size_t)S_;
  const int prow = wid * 16 + l16;
  for (int j = 0; j <= jmax; ++j) {
    const int cur = j & 1;
    if (j < jmax) {
      stageKb((cur ^ 1) * 4096, j + 1);
      stageVb(8192 + (cur ^ 1) * 4096, j + 1);
    }
    SCHED_PIN();   // staging issues stay ABOVE everything below (order = age)
    const unsigned short* pK = sKV + cur * 4096;
    const unsigned short* pV = sKV + 8192 + cur * 4096;
    f32x4 sc[4];
    const f32x4 zz = {0.f, 0.f, 0.f, 0.f};
#pragma unroll
    for (int ni = 0; ni < 4; ++ni) sc[ni] = zz;
#pragma unroll
    for (int ks = 0; ks < 2; ++ks)
#pragma unroll
      for (int ni = 0; ni < 4; ++ni) {
        int rr = ni * 16 + l16;
        bf16x8 kb = *(const bf16x8*)&pK[rr * 64 + (((ks * 4 + g16) ^ (rr & 7)) * 8)];
        sc[ni] = __builtin_amdgcn_mfma_f32_16x16x32_bf16(kb, qf[ks], sc[ni], 0, 0, 0);
      }
    const bool diag = (j == jmax);
#pragma unroll
    for (int ni = 0; ni < 4; ++ni) {
      const int colb = j * 64 + ni * 16 + g16 * 4;   // 4 consecutive attn cols
      f32x4 pv4;
      u16x4 pb4;
#pragma unroll
      for (int r = 0; r < 4; ++r) {
        float e = fexp2(sc[ni][r]) * invl;
        float p = (!diag || (colb + r <= scoreRow)) ? e : 0.f;
        pv4[r] = p;
        pb4[r] = f2bf(p);
      }
      *(f32x4*)(arowBase + colb) = pv4;              // 16B store
      const int cl = ni * 16 + g16 * 4;              // k-local col base
      *(u16x4*)&sP[prow * 64 + (((cl >> 3) ^ (prow & 7)) * 8) + (cl & 7)] = pb4;  // 8B
    }
    // PV: sP band is wave-private (write->read same wave, in-order LDS)
#pragma unroll
    for (int ks = 0; ks < 2; ++ks) {
      int pr = wid * 16 + l16;
      bf16x8 pa = *(const bf16x8*)&sP[pr * 64 + (((ks * 4 + g16) ^ (pr & 7)) * 8)];
#pragma unroll
      for (int ni = 0; ni < 4; ++ni) {
        int vr = ni * 16 + l16;
        bf16x8 vb = *(const bf16x8*)&pV[vr * 64 + (((ks * 4 + g16) ^ (vr & 7)) * 8)];
        oacc[ni] = __builtin_amdgcn_mfma_f32_16x16x32_bf16(pa, vb, oacc[ni], 0, 0, 0);
      }
    }
    WAIT_LGKM0();   // LDS reads of cur retired -> buffer reusable
    WAIT_VM4();     // 4 prefetch loads done; this iter's 4 stores may linger
    SCHED_PIN();
    BAR();          // all waves agree
  }

  // write O into concat layout [B,S,D], bf16 (oacc layout unchanged)
  const int bb = bh >> 4, hh = bh & 15;
#pragma unroll
  for (int ni = 0; ni < 4; ++ni)
#pragma unroll
    for (int r = 0; r < 4; ++r) {
      int srow = rowbase + r;
      Oc[((size_t)bb * S_ + srow) * D_ + hh * 64 + ni * 16 + l16] = f2bf(oacc[ni][r]);
    }

  // zero-fill above-diagonal attn columns (div-free: 4 threads per row)
  const int zstart = (jmax + 1) * 64;
  if (zstart < S_) {
    const f32x4 z4 = {0.f, 0.f, 0.f, 0.f};
    int r = tid >> 2;
    int c0 = zstart + (tid & 3) * 4;
    float* rowp = attn + ((size_t)bh * S_ + qBase + r) * (size_t)S_;
    for (int c = c0; c < S_; c += 16)
      *(f32x4*)(rowp + c) = z4;
  }
}

// ---------------------------------------------------------------- launch
extern "C" void kernel_launch(void* const* d_in, const int* in_sizes, int n_in,
                              void* d_out, int out_size, void* d_ws, size_t ws_size,
                              hipStream_t stream) {
  const float* q  = (const float*)d_in[0];
  const float* k  = (const float*)d_in[1];
  const float* v  = (const float*)d_in[2];
  // d_in[3] = causal mask (tril ones) — structure used directly
  const float* Wq = (const float*)d_in[4];
  const float* Wk = (const float*)d_in[5];
  const float* Wv = (const float*)d_in[6];
  const float* Wo = (const float*)d_in[7];

  float* out  = (float*)d_out;
  float* attn = out + (size_t)B_ * S_ * D_;

  // workspace layout (bf16 elements), total ~67 MB
  unsigned short* ws = (unsigned short*)d_ws;
  const size_t BSD = (size_t)B_ * S_ * D_;   // 4,194,304
  const size_t DD  = (size_t)D_ * D_;        // 1,048,576
  unsigned short* qb  = ws;
  unsigned short* kb  = qb + BSD;
  unsigned short* vb  = kb + BSD;
  unsigned short* wqb = vb + BSD;
  unsigned short* wkb = wqb + DD;
  unsigned short* wvb = wkb + DD;
  unsigned short* wob = wvb + DD;
  unsigned short* Qh  = wob + DD;
  unsigned short* Kh  = Qh + BSD;
  unsigned short* VhT = Kh + BSD;
  unsigned short* Oc  = VhT + BSD;

  const int n4 = (int)(BSD / 4);   // 1,048,576
  const int w4 = (int)(DD / 4);    // 262,144
  Cvt3 c3; c3.in[0] = q; c3.in[1] = k; c3.in[2] = v;
  c3.out[0] = qb; c3.out[1] = kb; c3.out[2] = vb;
  cvt3_kernel<<<dim3(n4 / 256, 3), 256, 0, stream>>>(c3, n4);
  Cvt4 c4; c4.in[0] = Wq; c4.in[1] = Wk; c4.in[2] = Wv; c4.in[3] = Wo;
  c4.out[0] = wqb; c4.out[1] = wkb; c4.out[2] = wvb; c4.out[3] = wob;
  cvt4_kernel<<<dim3(w4 / 256, 4), 256, 0, stream>>>(c4, w4);

  QKVArgs args;
  args.A[0] = qb;  args.A[1] = kb;  args.A[2] = vb;
  args.W[0] = wqb; args.W[1] = wkb; args.W[2] = wvb;
  args.O[0] = Qh;  args.O[1] = Kh;  args.O[2] = VhT;
  gemm_qkv<<<dim3(32, 8, 3), 256, 0, stream>>>(args);

  attn_kernel<<<dim3(32, 32), 256, 0, stream>>>(Qh, Kh, VhT, attn, Oc);

  gemm_out<<<dim3(32, 16), 256, 0, stream>>>(Oc, wob, out);
}